// Round 11
// baseline (78.989 us; speedup 1.0000x reference)
//
#include <hip/hip_runtime.h>
#include <math.h>

// WavefunctionEmbedding, fully fused single kernel (NO workspace):
//   out[b,i,2k+0/1] = sum_j amp_ij * {cos,sin}(wn_k * r_ij)
// Block owns ROWS=4 rows: radial histograms in LDS (cubic Lagrange deposit,
// int32 fixed-point ds_add), then in-block contraction against
// cos/sin(wn_k * r_q) via per-thread Chebyshev recurrence.
//
// R11 changes vs R9 (best, 75.4 total ~= 54 harness floor + ~21 us kernel):
//  - Contraction no longer streams the histogram through the LDS pipe
//    (R9: 132 broadcast ds_read_b128/thread; LDS pipe is the per-CU serial
//    resource shared with the deposits' ds_add). Each wave now loads the
//    whole 4x260 hist into 20 VGPRs with conflict-free ds_read_b32, then
//    broadcasts per-q values via v_readlane (VALU path, zero LDS ops),
//    q-loop fully unrolled per 64-lane chunk.
//  - hist row stride 320 (5 x 64) so each row is 5 full wave chunks;
//    bins 260..319 stay zero (deposits reach at most index 258).
//  - deposit: fract(u) replaces floorf+sub. Weights/h otherwise identical.

#define N_FIXED  1536
#define K_FIXED  256
#define QBINS    256
#define QG       260            // node q represents r = (q-1)*h
#define ROWS     4              // rows per block (768 blocks = 3/CU exact)
#define RSTRIDE  320            // hist row stride in ints (5 x 64)
#define NTHREADS 512
#define FPSCALE  4194304.0f     // 2^22 fixed-point scale for hist deposits

__device__ __forceinline__ float rdlane(float v, int l) {
    return __int_as_float(__builtin_amdgcn_readlane(__float_as_int(v), l));
}

// ---------------- fallback: direct kernel (round-1, known-good) ------------
__global__ __launch_bounds__(256) void wf_direct_kernel(
    const float* __restrict__ coords, const unsigned char* __restrict__ mask,
    const float* __restrict__ wavenumbers, float* __restrict__ out, int N, int K)
{
    __shared__ float2 pairs[N_FIXED];
    const int row = blockIdx.x;
    const int b   = row / N;
    const int i   = row - b * N;
    const int t   = threadIdx.x;
    const float* crow = coords + (size_t)b * N * 3;
    const float xi = crow[i*3+0], yi = crow[i*3+1], zi = crow[i*3+2];
    const unsigned char* mrow = mask + (size_t)b * N;
    for (int j = t; j < N; j += blockDim.x) {
        float dx = crow[j*3+0]-xi, dy = crow[j*3+1]-yi, dz = crow[j*3+2]-zi;
        float d2 = fmaf(dx,dx, fmaf(dy,dy, fmaf(dz,dz, 1e-12f)));
        float r  = sqrtf(d2);
        float amp = 0.07957747154594767f / fmaxf(r, 1e-6f);
        if (j == i || mrow[j]) amp = 0.0f;
        pairs[j] = make_float2(r, amp);
    }
    __syncthreads();
    const int k = t;
    const float f = wavenumbers[k] * 0.15915494309189535f;
    float re = 0.0f, im = 0.0f;
    #pragma unroll 4
    for (int j = 0; j < N; ++j) {
        float2 p = pairs[j];
        float x  = __builtin_amdgcn_fractf(p.x * f);
        float c  = __builtin_amdgcn_cosf(x);
        float s  = __builtin_amdgcn_sinf(x);
        re = fmaf(c, p.y, re);
        im = fmaf(s, p.y, im);
    }
    float2* orow = (float2*)out + (size_t)row * K;
    orow[k] = make_float2(re, im);
}

// ---------------- fused: hist + register-broadcast contraction -------------
__global__ __launch_bounds__(NTHREADS) void wf_fused_kernel(
    const float* __restrict__ coords, const unsigned char* __restrict__ mask,
    const float* __restrict__ wavenumbers, float* __restrict__ out, int N)
{
    __shared__ int    hist[ROWS * RSTRIDE];        // 5 KB, r-major
    __shared__ float  red[8];
    __shared__ float2 merge[ROWS * K_FIXED];       // 8 KB team-1 partials

    const int i0 = blockIdx.x * ROWS;      // first global row of this block
    const int b  = i0 / N;                 // N % ROWS == 0 -> block within b
    const int t  = threadIdx.x;

    const float* crow = coords + (size_t)b * N * 3;
    const unsigned char* mrow = mask + (size_t)b * N;

    // ---- rmax over THIS BATCH only (h is per-block-consistent) ----
    float m = 0.0f;
    #pragma unroll
    for (int s = 0; s < N_FIXED / NTHREADS; ++s) {
        const int p = t + NTHREADS * s;
        float x = crow[3*p], y = crow[3*p+1], z = crow[3*p+2];
        m = fmaxf(m, fmaf(x,x, fmaf(y,y, z*z)));
    }
    #pragma unroll
    for (int off = 32; off >= 1; off >>= 1)
        m = fmaxf(m, __shfl_down(m, off, 64));
    if ((t & 63) == 0) red[t >> 6] = m;
    for (int a = t; a < ROWS * RSTRIDE; a += NTHREADS) hist[a] = 0;
    __syncthreads();
    float mm = red[0];
    #pragma unroll
    for (int w = 1; w < 8; ++w) mm = fmaxf(mm, red[w]);
    const float rmax = 2.0005f * sqrtf(mm) + 1e-3f;   // r_ij <= 2 max|c|
    const float h    = rmax / (float)QBINS;           // => u = r/h < 256
    const float inv_h = 1.0f / h;

    // ---- histograms: each j loaded once, deposit into all ROWS rows ----
    const int il0 = i0 - b * N;            // local i of row 0
    float cx[ROWS], cy[ROWS], cz[ROWS];
    #pragma unroll
    for (int r = 0; r < ROWS; ++r) {
        cx[r] = crow[3*(il0+r)];
        cy[r] = crow[3*(il0+r)+1];
        cz[r] = crow[3*(il0+r)+2];
    }

    #pragma unroll
    for (int s = 0; s < N_FIXED / NTHREADS; ++s) {
        const int j = t + NTHREADS * s;
        const float xj = crow[3*j], yj = crow[3*j+1], zj = crow[3*j+2];
        const bool masked = (mrow[j] != 0);
        #pragma unroll
        for (int r = 0; r < ROWS; ++r) {
            float dx = xj - cx[r];
            float dy = yj - cy[r];
            float dz = zj - cz[r];
            float d2 = fmaf(dx,dx, fmaf(dy,dy, fmaf(dz,dz, 1e-12f)));
            float rsq = __builtin_amdgcn_rsqf(d2);     // 1/r, r >= 1e-6
            float amp = 0.07957747154594767f * rsq;    // 1/(4 pi r)
            if (j == il0 + r || masked) amp = 0.0f;

            float u  = d2 * rsq * inv_h;               // r/h, in [0,256)
            int   q0 = (int)u;                         // trunc = floor (u>=0)
            float tt = __builtin_amdgcn_fractf(u);
            // Lagrange cubic through nodes {-1,0,1,2} at offset tt in [0,1)
            float as6 = amp * (FPSCALE * (1.0f/6.0f));
            float as2 = amp * (FPSCALE * 0.5f);
            float tm1 = tt + 1.0f, t1 = tt - 1.0f, t2 = tt - 2.0f;
            float p  = tt  * t1;                       // t(t-1)
            float qq = tm1 * t2;                       // (t+1)(t-2)
            int w0 = (int)(-(p  * t2)  * as6);         // truncating cvt
            int w1 = (int)( (qq * t1)  * as2);
            int w2 = (int)(-(qq * tt)  * as2);
            int w3 = (int)( (p  * tm1) * as6);
            int* hb = &hist[r * RSTRIDE + q0];
            atomicAdd(hb + 0, w0);                     // native ds_add
            atomicAdd(hb + 1, w1);
            atomicAdd(hb + 2, w2);
            atomicAdd(hb + 3, w3);
        }
    }
    __syncthreads();

    // ---- convert int -> float in place ----
    float* hf = (float*)hist;
    const float invS = 1.0f / FPSCALE;
    for (int a = t; a < ROWS * RSTRIDE; a += NTHREADS)
        hf[a] = (float)hist[a] * invS;
    __syncthreads();

    // ---- load whole hist into registers: 20 conflict-free ds_read_b32 ----
    const int lane = t & 63;
    float hr[ROWS][5];
    #pragma unroll
    for (int r = 0; r < ROWS; ++r)
        #pragma unroll
        for (int c = 0; c < 5; ++c)
            hr[r][c] = hf[r * RSTRIDE + c * 64 + lane];

    // ---- contraction: team = q-half, readlane broadcast (no LDS pipe) ----
    const int team = t >> 8;               // 0 or 1
    const int col  = t & 255;              // col-pair index
    const int qs   = team ? 128 : 0;       // team 0: q 0..127, team 1: 128..259

    const float xrev = wavenumbers[col] * 0.15915494309189535f * h;
    const float k2   = 2.0f * __builtin_amdgcn_cosf(__builtin_amdgcn_fractf(xrev));
    const float aarg = __builtin_amdgcn_fractf((float)(qs - 1) * xrev);
    const float barg = __builtin_amdgcn_fractf((float)qs * xrev);
    float ca = __builtin_amdgcn_cosf(aarg), sa = __builtin_amdgcn_sinf(aarg);
    float cb = __builtin_amdgcn_cosf(barg), sb = __builtin_amdgcn_sinf(barg);

    float are[ROWS], aim[ROWS];
    #pragma unroll
    for (int r = 0; r < ROWS; ++r) { are[r] = 0.0f; aim[r] = 0.0f; }

    #define QSTEP(c, l)                                                        \
        do {                                                                   \
            const float h0 = rdlane(hr[0][c], l);                              \
            const float h1 = rdlane(hr[1][c], l);                              \
            const float h2 = rdlane(hr[2][c], l);                              \
            const float h3 = rdlane(hr[3][c], l);                              \
            are[0] = fmaf(h0, ca, are[0]); aim[0] = fmaf(h0, sa, aim[0]);      \
            are[1] = fmaf(h1, ca, are[1]); aim[1] = fmaf(h1, sa, aim[1]);      \
            are[2] = fmaf(h2, ca, are[2]); aim[2] = fmaf(h2, sa, aim[2]);      \
            are[3] = fmaf(h3, ca, are[3]); aim[3] = fmaf(h3, sa, aim[3]);      \
            const float cn = fmaf(k2, cb, -ca);                                \
            const float sn = fmaf(k2, sb, -sa);                                \
            ca = cb; cb = cn; sa = sb; sb = sn;                                \
        } while (0)

    if (team == 0) {
        #pragma unroll
        for (int l = 0; l < 64; ++l) QSTEP(0, l);
        #pragma unroll
        for (int l = 0; l < 64; ++l) QSTEP(1, l);
    } else {
        #pragma unroll
        for (int l = 0; l < 64; ++l) QSTEP(2, l);
        #pragma unroll
        for (int l = 0; l < 64; ++l) QSTEP(3, l);
        #pragma unroll
        for (int l = 0; l < 4; ++l)  QSTEP(4, l);      // q = 256..259
    }
    #undef QSTEP

    // ---- merge team 1 into team 0, store ----
    if (team == 1) {
        #pragma unroll
        for (int r = 0; r < ROWS; ++r)
            merge[r * K_FIXED + col] = make_float2(are[r], aim[r]);
    }
    __syncthreads();
    if (team == 0) {
        #pragma unroll
        for (int r = 0; r < ROWS; ++r) {
            const float2 p = merge[r * K_FIXED + col];
            ((float2*)out)[(size_t)(i0 + r) * K_FIXED + col] =
                make_float2(are[r] + p.x, aim[r] + p.y);
        }
    }
}

extern "C" void kernel_launch(void* const* d_in, const int* in_sizes, int n_in,
                              void* d_out, int out_size, void* d_ws, size_t ws_size,
                              hipStream_t stream) {
    const float* coords          = (const float*)d_in[0];
    const unsigned char* mask    = (const unsigned char*)d_in[1];
    const float* wavenumbers     = (const float*)d_in[2];
    float* out                   = (float*)d_out;

    const int K  = in_sizes[2];
    const int BN = in_sizes[0] / 3;        // B*N
    const int N  = N_FIXED;

    if (K != K_FIXED || BN % N != 0 || (N % ROWS) != 0 ||
        (N % NTHREADS) != 0) {
        wf_direct_kernel<<<BN, K, 0, stream>>>(coords, mask, wavenumbers, out, N, K);
        return;
    }

    wf_fused_kernel<<<BN / ROWS, NTHREADS, 0, stream>>>(coords, mask,
                                                        wavenumbers, out, N);
}

// Round 12
// 74.006 us; speedup vs baseline: 1.0673x; 1.0673x over previous
//
#include <hip/hip_runtime.h>
#include <math.h>

// WavefunctionEmbedding, fully fused single kernel (NO workspace):
//   out[b,i,2k+0/1] = sum_j amp_ij * {cos,sin}(wn_k * r_ij)
// Block owns ROWS=4 rows: radial histograms in LDS (cubic Lagrange deposit,
// int32 fixed-point ds_add), then in-block contraction against
// cos/sin(wn_k * r_q) via per-thread Chebyshev recurrence.
//
// R12 = R9 (best, 75.4 total ~= 55 us harness floor + ~20 us kernel) with the
// contraction rewritten in 2-wide packed fp32 (v_pk_fma_f32 via ext_vector +
// __builtin_elementwise_fma):
//   - acc: (re,im) pairs -> 4 packed FMA/q instead of 8 scalar
//   - Chebyshev: (cos,sin) tracks share coefficient k2 -> 1 packed FMA/q
//     instead of 2 scalar
//   10 -> 5 wave-ops per q in the dominant phase. All arithmetic values
//   identical to R9 -> absmax must stay 0.03125.
// (R11's readlane experiment regressed: readlane is a VALU op per value, so
// it REPLACED 132 LDS broadcasts with 1040 VALU ops. Reverted.)

#define N_FIXED  1536
#define K_FIXED  256
#define QBINS    256
#define QG       260            // node q represents r = (q-1)*h
#define ROWS     4              // rows per block (768 blocks = 3/CU)
#define RSTRIDE  272            // hist row stride in floats (16B-aligned)
#define NTHREADS 512
#define FPSCALE  4194304.0f     // 2^22 fixed-point scale for hist deposits

typedef __attribute__((ext_vector_type(2))) float f32x2;

// ---------------- fallback: direct kernel (round-1, known-good) ------------
__global__ __launch_bounds__(256) void wf_direct_kernel(
    const float* __restrict__ coords, const unsigned char* __restrict__ mask,
    const float* __restrict__ wavenumbers, float* __restrict__ out, int N, int K)
{
    __shared__ float2 pairs[N_FIXED];
    const int row = blockIdx.x;
    const int b   = row / N;
    const int i   = row - b * N;
    const int t   = threadIdx.x;
    const float* crow = coords + (size_t)b * N * 3;
    const float xi = crow[i*3+0], yi = crow[i*3+1], zi = crow[i*3+2];
    const unsigned char* mrow = mask + (size_t)b * N;
    for (int j = t; j < N; j += blockDim.x) {
        float dx = crow[j*3+0]-xi, dy = crow[j*3+1]-yi, dz = crow[j*3+2]-zi;
        float d2 = fmaf(dx,dx, fmaf(dy,dy, fmaf(dz,dz, 1e-12f)));
        float r  = sqrtf(d2);
        float amp = 0.07957747154594767f / fmaxf(r, 1e-6f);
        if (j == i || mrow[j]) amp = 0.0f;
        pairs[j] = make_float2(r, amp);
    }
    __syncthreads();
    const int k = t;
    const float f = wavenumbers[k] * 0.15915494309189535f;
    float re = 0.0f, im = 0.0f;
    #pragma unroll 4
    for (int j = 0; j < N; ++j) {
        float2 p = pairs[j];
        float x  = __builtin_amdgcn_fractf(p.x * f);
        float c  = __builtin_amdgcn_cosf(x);
        float s  = __builtin_amdgcn_sinf(x);
        re = fmaf(c, p.y, re);
        im = fmaf(s, p.y, im);
    }
    float2* orow = (float2*)out + (size_t)row * K;
    orow[k] = make_float2(re, im);
}

// ---------------- fused: hist + packed in-block contraction ----------------
__global__ __launch_bounds__(NTHREADS) void wf_fused_kernel(
    const float* __restrict__ coords, const unsigned char* __restrict__ mask,
    const float* __restrict__ wavenumbers, float* __restrict__ out, int N)
{
    __shared__ int   hist[ROWS * RSTRIDE];         // 4.25 KB, r-major
    __shared__ float red[8];
    __shared__ f32x2 merge[ROWS * K_FIXED];        // 8 KB team-1 partials

    const int i0 = blockIdx.x * ROWS;      // first global row of this block
    const int b  = i0 / N;                 // N % ROWS == 0 -> block within b
    const int t  = threadIdx.x;

    const float* crow = coords + (size_t)b * N * 3;
    const unsigned char* mrow = mask + (size_t)b * N;

    // ---- rmax over THIS BATCH only (h is per-block-consistent) ----
    float m = 0.0f;
    #pragma unroll
    for (int s = 0; s < N_FIXED / NTHREADS; ++s) {
        const int p = t + NTHREADS * s;
        float x = crow[3*p], y = crow[3*p+1], z = crow[3*p+2];
        m = fmaxf(m, fmaf(x,x, fmaf(y,y, z*z)));
    }
    #pragma unroll
    for (int off = 32; off >= 1; off >>= 1)
        m = fmaxf(m, __shfl_down(m, off, 64));
    if ((t & 63) == 0) red[t >> 6] = m;
    for (int a = t; a < ROWS * RSTRIDE; a += NTHREADS) hist[a] = 0;
    __syncthreads();
    float mm = red[0];
    #pragma unroll
    for (int w = 1; w < 8; ++w) mm = fmaxf(mm, red[w]);
    const float rmax = 2.0005f * sqrtf(mm) + 1e-3f;   // r_ij <= 2 max|c|
    const float h    = rmax / (float)QBINS;           // => u = r/h < 256
    const float inv_h = 1.0f / h;

    // ---- histograms: each j loaded once, deposit into all ROWS rows ----
    const int il0 = i0 - b * N;            // local i of row 0
    float cx[ROWS], cy[ROWS], cz[ROWS];
    #pragma unroll
    for (int r = 0; r < ROWS; ++r) {
        cx[r] = crow[3*(il0+r)];
        cy[r] = crow[3*(il0+r)+1];
        cz[r] = crow[3*(il0+r)+2];
    }

    #pragma unroll
    for (int s = 0; s < N_FIXED / NTHREADS; ++s) {
        const int j = t + NTHREADS * s;
        const float xj = crow[3*j], yj = crow[3*j+1], zj = crow[3*j+2];
        const bool masked = (mrow[j] != 0);
        #pragma unroll
        for (int r = 0; r < ROWS; ++r) {
            float dx = xj - cx[r];
            float dy = yj - cy[r];
            float dz = zj - cz[r];
            float d2 = fmaf(dx,dx, fmaf(dy,dy, fmaf(dz,dz, 1e-12f)));
            float rsq = __builtin_amdgcn_rsqf(d2);     // 1/r, r >= 1e-6
            float amp = 0.07957747154594767f * rsq;    // 1/(4 pi r)
            if (j == il0 + r || masked) amp = 0.0f;

            float u  = d2 * rsq * inv_h;               // r/h, in [0,256)
            float qf = floorf(u);
            int   q0 = (int)qf;                        // 0..255, no clamp
            float tt = u - qf;
            // Lagrange cubic through nodes {-1,0,1,2} at offset tt in [0,1)
            float as6 = amp * (FPSCALE * (1.0f/6.0f));
            float as2 = amp * (FPSCALE * 0.5f);
            float tm1 = tt + 1.0f, t1 = tt - 1.0f, t2 = tt - 2.0f;
            float p  = tt  * t1;                       // t(t-1)
            float qq = tm1 * t2;                       // (t+1)(t-2)
            int w0 = (int)(-(p  * t2)  * as6);         // truncating cvt
            int w1 = (int)( (qq * t1)  * as2);
            int w2 = (int)(-(qq * tt)  * as2);
            int w3 = (int)( (p  * tm1) * as6);
            int* hb = &hist[r * RSTRIDE + q0];
            atomicAdd(hb + 0, w0);                     // native ds_add
            atomicAdd(hb + 1, w1);
            atomicAdd(hb + 2, w2);
            atomicAdd(hb + 3, w3);
        }
    }
    __syncthreads();

    // ---- convert int -> float in place (each slot one thread) ----
    float* hf = (float*)hist;
    const float invS = 1.0f / FPSCALE;
    for (int a = t; a < ROWS * RSTRIDE; a += NTHREADS)
        hf[a] = (float)hist[a] * invS;
    __syncthreads();

    // ---- contraction: team = q-half, thread owns col-pair c for 4 rows ----
    const int team = t >> 8;               // 0 or 1
    const int c    = t & 255;              // col-pair index
    const int gbeg = team ? 33 : 0;        // groups of 4 q-nodes
    const int gend = team ? 65 : 33;       // 65 groups cover q 0..259
    const int qs   = gbeg * 4;

    // theta (revolutions per node) = wn_c * h / 2pi
    const float xrev = wavenumbers[c] * 0.15915494309189535f * h;
    const float k2s  = 2.0f * __builtin_amdgcn_cosf(__builtin_amdgcn_fractf(xrev));
    const f32x2 k2   = {k2s, k2s};
    // Chebyshev seeds: w_a = cis((qs-1)*th), w_b = cis(qs*th); both (cos,sin)
    // tracks advance with the same 3-term recurrence -> packed.
    const float aarg = __builtin_amdgcn_fractf((float)(qs - 1) * xrev);
    const float barg = __builtin_amdgcn_fractf((float)qs * xrev);
    f32x2 wa = {__builtin_amdgcn_cosf(aarg), __builtin_amdgcn_sinf(aarg)};
    f32x2 wb = {__builtin_amdgcn_cosf(barg), __builtin_amdgcn_sinf(barg)};

    f32x2 acc[ROWS];
    #pragma unroll
    for (int r = 0; r < ROWS; ++r) acc[r] = (f32x2){0.0f, 0.0f};

    #pragma unroll 2
    for (int g = gbeg; g < gend; ++g) {
        const int q0 = g * 4;
        const float4 h0 = *(const float4*)&hf[0 * RSTRIDE + q0]; // ds_read_b128
        const float4 h1 = *(const float4*)&hf[1 * RSTRIDE + q0];
        const float4 h2 = *(const float4*)&hf[2 * RSTRIDE + q0];
        const float4 h3 = *(const float4*)&hf[3 * RSTRIDE + q0];
        const float r0[4] = {h0.x, h0.y, h0.z, h0.w};
        const float r1[4] = {h1.x, h1.y, h1.z, h1.w};
        const float r2[4] = {h2.x, h2.y, h2.z, h2.w};
        const float r3[4] = {h3.x, h3.y, h3.z, h3.w};
        #pragma unroll
        for (int d = 0; d < 4; ++d) {
            // packed acc: v_pk_fma_f32 (splat h, multiply (cos,sin), add acc)
            acc[0] = __builtin_elementwise_fma((f32x2){r0[d], r0[d]}, wa, acc[0]);
            acc[1] = __builtin_elementwise_fma((f32x2){r1[d], r1[d]}, wa, acc[1]);
            acc[2] = __builtin_elementwise_fma((f32x2){r2[d], r2[d]}, wa, acc[2]);
            acc[3] = __builtin_elementwise_fma((f32x2){r3[d], r3[d]}, wa, acc[3]);
            // packed Chebyshev step: w_{q+1} = k2*w_q - w_{q-1}
            const f32x2 wn = __builtin_elementwise_fma(k2, wb, -wa);
            wa = wb; wb = wn;
        }
    }

    // ---- merge team 1 into team 0, store ----
    if (team == 1) {
        #pragma unroll
        for (int r = 0; r < ROWS; ++r)
            merge[r * K_FIXED + c] = acc[r];
    }
    __syncthreads();
    if (team == 0) {
        #pragma unroll
        for (int r = 0; r < ROWS; ++r) {
            const f32x2 p = merge[r * K_FIXED + c];
            const f32x2 v = acc[r] + p;
            ((float2*)out)[(size_t)(i0 + r) * K_FIXED + c] =
                make_float2(v.x, v.y);
        }
    }
}

extern "C" void kernel_launch(void* const* d_in, const int* in_sizes, int n_in,
                              void* d_out, int out_size, void* d_ws, size_t ws_size,
                              hipStream_t stream) {
    const float* coords          = (const float*)d_in[0];
    const unsigned char* mask    = (const unsigned char*)d_in[1];
    const float* wavenumbers     = (const float*)d_in[2];
    float* out                   = (float*)d_out;

    const int K  = in_sizes[2];
    const int BN = in_sizes[0] / 3;        // B*N
    const int N  = N_FIXED;

    if (K != K_FIXED || BN % N != 0 || (N % ROWS) != 0 ||
        (N % NTHREADS) != 0) {
        wf_direct_kernel<<<BN, K, 0, stream>>>(coords, mask, wavenumbers, out, N, K);
        return;
    }

    wf_fused_kernel<<<BN / ROWS, NTHREADS, 0, stream>>>(coords, mask,
                                                        wavenumbers, out, N);
}